// Round 7
// baseline (3976.383 us; speedup 1.0000x reference)
//
#include <hip/hip_runtime.h>
#include <hip/hip_bf16.h>
#include <stdint.h>

#define B_    64
#define T_    1024
#define DIN   136
#define DINP  160
#define H_    256
#define G4H   1024
#define SEG   256
#define NSEG  4

typedef __bf16 bf16;
typedef _Float16 f16;
typedef __bf16 bf16x8 __attribute__((ext_vector_type(8)));
typedef float  floatx4 __attribute__((ext_vector_type(4)));
typedef int    int4v  __attribute__((ext_vector_type(4)));
typedef _Float16 half4 __attribute__((ext_vector_type(4)));

__device__ __forceinline__ float fsigm(float x) {
  return __builtin_amdgcn_rcpf(1.f + __builtin_amdgcn_exp2f(x * -1.4426950408889634f));
}
__device__ __forceinline__ float ftanh(float x) {
  float e = __builtin_amdgcn_exp2f(x * 2.8853900817779268f);   // e^(2x); inf/0-safe
  return 1.f - 2.f * __builtin_amdgcn_rcpf(e + 1.f);
}

// ---------------- pack: Wih bf16 (rows packed r=4*hid+gate, k padded to 160) ----------------
__global__ void k_pack_wih(const float* __restrict__ wf, const float* __restrict__ wb,
                           bf16* __restrict__ wp) {
  const int n = 2 * G4H * DINP;
  for (int i = blockIdx.x * blockDim.x + threadIdx.x; i < n; i += gridDim.x * blockDim.x) {
    int k   = i % DINP;
    int r   = (i / DINP) & (G4H - 1);
    int dir = i / (G4H * DINP);
    int orig = ((r & 3) << 8) | (r >> 2);
    const float* w = dir ? wb : wf;
    float v = (k < DIN) ? w[orig * DIN + k] : 0.f;
    wp[i] = (bf16)v;
  }
}

__global__ void k_pack_bias(const float* __restrict__ bihf, const float* __restrict__ bhhf,
                            const float* __restrict__ bihb, const float* __restrict__ bhhb,
                            float* __restrict__ bs) {
  int i = blockIdx.x * blockDim.x + threadIdx.x;
  if (i >= 2 * G4H) return;
  int r = i & (G4H - 1); int dir = i >> 10;
  int orig = ((r & 3) << 8) | (r >> 2);
  bs[i] = dir ? (bihb[orig] + bhhb[orig]) : (bihf[orig] + bhhf[orig]);
}

// ---------------- pack: Whh -> i8 A-fragments + per-16-row-tile scales ----------------
// Frag: w8[((dir*64+Tt)*4+c)*64 + l] (16B): lane l=(q,m): A row=Tt*16+m, k=c*64+q*16+j.
// scales[dir*64+Tt] = amax/(127*127*256): dequant for acc = 256*Sum(W*hi) + Sum(W*lo).
__global__ __launch_bounds__(256) void k_pack_whh8(
    const float* __restrict__ wf_, const float* __restrict__ wb_,
    char* __restrict__ w8, float* __restrict__ scales)
{
  __shared__ float red[4];
  const int bx  = blockIdx.x;          // 0..127 = dir*64 + tile
  const int dir = bx >> 6, Tt = bx & 63;
  const float* w = dir ? wb_ : wf_;
  const int tid = threadIdx.x;
  const int c = tid >> 6, l = tid & 63, q = l >> 4, m = l & 15;
  const int prow = Tt * 16 + m;
  const int orig = ((prow & 3) << 8) | (prow >> 2);

  float v[16]; float am = 0.f;
#pragma unroll
  for (int j = 0; j < 16; ++j) {
    v[j] = w[orig * H_ + c * 64 + q * 16 + j];
    am = fmaxf(am, fabsf(v[j]));
  }
#pragma unroll
  for (int off = 32; off; off >>= 1) am = fmaxf(am, __shfl_xor(am, off));
  if (l == 0) red[tid >> 6] = am;
  __syncthreads();
  am = fmaxf(fmaxf(red[0], red[1]), fmaxf(red[2], red[3]));
  am = fmaxf(am, 1e-30f);
  float qs = 127.f / am;

  int4v o;
#pragma unroll
  for (int d = 0; d < 4; ++d) {
    unsigned a8 = 0;
#pragma unroll
    for (int jj = 0; jj < 4; ++jj) {
      int bi = (int)rintf(v[d * 4 + jj] * qs);
      a8 |= ((unsigned)bi & 0xFFu) << (8 * jj);
    }
    o[d] = (int)a8;
  }
  ((int4v*)w8)[((size_t)(dir * 64 + Tt) * 4 + c) * 64 + l] = o;
  if (tid == 0) scales[dir * 64 + Tt] = am / (127.f * 127.f * 256.f);
}

// ---------------- x-projection (per segment): xps[dir][j][b][1024] f16 ----------------
// j = local step (iteration order); actual time = dir ? T-1-(g0+j) : g0+j.
__global__ __launch_bounds__(256) void k_xproj(
    const float* __restrict__ x, const bf16* __restrict__ wihp,
    const float* __restrict__ bs, f16* __restrict__ xps, int seg)
{
  const int tid = threadIdx.x;
  const int wv = tid >> 6, l = tid & 63, q = l >> 4, m = l & 15;
  const int W = blockIdx.x * 4 + wv;           // 0..2047
  const int dir = W >> 10;
  const int r = W & 1023;
  const int j = r >> 2, b0 = (r & 3) * 16;
  const int xt = dir ? (T_ - 1 - (seg * SEG + j)) : (seg * SEG + j);

  bf16x8 a[5];
  {
    const float* xr = x + ((size_t)(b0 + m) * T_ + xt) * DIN;
#pragma unroll
    for (int c = 0; c < 5; ++c) {
      bf16x8 av;
#pragma unroll
      for (int j8 = 0; j8 < 8; ++j8) {
        int k = c * 32 + q * 8 + j8;
        av[j8] = (k < DIN) ? (bf16)xr[k] : (bf16)0.f;
      }
      a[c] = av;
    }
  }

  for (int nt = 0; nt < 64; ++nt) {
    int col = nt * 16 + m;
    float bv = bs[dir * G4H + col];
    floatx4 acc = {bv, bv, bv, bv};
    const bf16* wr = wihp + (size_t)(dir * G4H + col) * DINP + q * 8;
#pragma unroll
    for (int c = 0; c < 5; ++c)
      acc = __builtin_amdgcn_mfma_f32_16x16x32_bf16(a[c], *(const bf16x8*)(wr + c * 32), acc, 0, 0, 0);
#pragma unroll
    for (int jj = 0; jj < 4; ++jj)
      xps[((size_t)(dir * SEG + j) * B_ + b0 + q * 4 + jj) * G4H + col] = (f16)acc[jj];
  }
}

// ---------------- persistent-per-segment LSTM: one wg per (dir,btile), NO cross-CU sync ----------------
// 8 wgs x 1024 thr (16 waves/CU). Wave wv owns 64 packed gate rows (16 hid) x 16 batch.
// Whh i8 A-frags in VGPRs; h via LDS as i8 hi+lo planes (double-buffered); one barrier/step.
// Single i32 acc per tile: acc = 256*Sum_hi_chunks + Sum_lo_chunks (|acc|max ~1.06e9 < 2^31).
// (c,h) carried across segments in `state` (written seg s, read seg s+1; never read at s=0).
__global__ __launch_bounds__(1024, 1) void k_lstm(
    const int4v* __restrict__ whh8, const float* __restrict__ scales,
    const f16* __restrict__ xps, bf16* __restrict__ hseg,
    float* __restrict__ state, int seg)
{
  __shared__ char hsm[16384];   // [parity2][plane2][chunk4][1024B frag-linear]

  const int tid = threadIdx.x;
  const int wv = tid >> 6, l = tid & 63, q = l >> 4, m = l & 15;
  const int bx = blockIdx.x;           // 0..7 = dir*4 + btile
  const int dir = bx >> 2, btile = bx & 3;

  int4v wf[4][4];
#pragma unroll
  for (int tl = 0; tl < 4; ++tl)
#pragma unroll
    for (int c = 0; c < 4; ++c)
      wf[tl][c] = whh8[((size_t)(dir * 64 + wv * 4 + tl) * 4 + c) * 64 + l];

  float scl[4];
#pragma unroll
  for (int tl = 0; tl < 4; ++tl) {
    float s = scales[dir * 64 + wv * 4 + tl];
    scl[tl] = __builtin_bit_cast(float, __builtin_amdgcn_readfirstlane(__builtin_bit_cast(int, s)));
  }

  unsigned* const hseg_dw = (unsigned*)hseg;
  const int cw = wv >> 2;                       // k-chunk of this wave's hids
  const int fl16 = (((wv & 3) * 16) + m) * 16;  // byte base within chunk page

  float cst[4] = {0.f, 0.f, 0.f, 0.f};
  float hvf[4] = {0.f, 0.f, 0.f, 0.f};

  if (seg > 0) {
    const floatx4* sp = (const floatx4*)(state + ((size_t)bx * 1024 + tid) * 8);
    floatx4 s0 = sp[0], s1 = sp[1];
#pragma unroll
    for (int tl = 0; tl < 4; ++tl) { cst[tl] = s0[tl]; hvf[tl] = s1[tl]; }
    // rebuild h(g0-1) LDS planes at parity 1 (g0 even -> (g0-1)&1 == 1)
#pragma unroll
    for (int tl = 0; tl < 4; ++tl) {
      float t127 = hvf[tl] * 127.f;
      float fhi  = rintf(t127);
      float flo  = fminf(fmaxf(rintf((t127 - fhi) * 256.f), -127.f), 127.f);
      int waddr = ((1 * 2 + 0) * 4 + cw) * 1024 + fl16 + tl * 4 + q;
      hsm[waddr]        = (char)(int)fhi;
      hsm[waddr + 4096] = (char)(int)flo;
    }
  }

  half4 nxt[4];
  {
    const f16* ip = xps + ((size_t)(dir * SEG + 0) * B_ + btile * 16 + m) * G4H + wv * 64 + q * 4;
#pragma unroll
    for (int tl = 0; tl < 4; ++tl) nxt[tl] = *(const half4*)(ip + tl * 16);
  }

  for (int j = 0; j < SEG; ++j) {
    const int tg = seg * SEG + j;
    int4v a[4] = {{0,0,0,0},{0,0,0,0},{0,0,0,0},{0,0,0,0}};

    if (tg > 0) {
      __syncthreads();                 // h(tg-1) planes complete (incl. seg-start rebuild)
      const int pr = (tg & 1) ^ 1;
#pragma unroll
      for (int c = 0; c < 4; ++c) {
        int4v bhi = *(const int4v*)(hsm + ((pr * 2 + 0) * 4 + c) * 1024 + l * 16);
#pragma unroll
        for (int tl = 0; tl < 4; ++tl)
          a[tl] = __builtin_amdgcn_mfma_i32_16x16x64_i8(wf[tl][c], bhi, a[tl], 0, 0, 0);
      }
#pragma unroll
      for (int tl = 0; tl < 4; ++tl) a[tl] = a[tl] * 256;
#pragma unroll
      for (int c = 0; c < 4; ++c) {
        int4v blo = *(const int4v*)(hsm + ((pr * 2 + 1) * 4 + c) * 1024 + l * 16);
#pragma unroll
        for (int tl = 0; tl < 4; ++tl)
          a[tl] = __builtin_amdgcn_mfma_i32_16x16x64_i8(wf[tl][c], blo, a[tl], 0, 0, 0);
      }
    }

    // cell update: per tile -> one (hid,b) cell; regs j = gates i,f,g,o
    unsigned short hu[4];
    const int pw = tg & 1;
#pragma unroll
    for (int tl = 0; tl < 4; ++tl) {
      float s = scl[tl];
      float pi = (float)nxt[tl][0] + (float)a[tl][0] * s;
      float pf = (float)nxt[tl][1] + (float)a[tl][1] * s;
      float pg = (float)nxt[tl][2] + (float)a[tl][2] * s;
      float po = (float)nxt[tl][3] + (float)a[tl][3] * s;
      float ig = fsigm(pi);
      float fg = fsigm(pf);
      float og = fsigm(po);
      float gg = ftanh(pg);
      float c  = fg * cst[tl] + ig * gg;
      cst[tl]  = c;
      float hv = og * ftanh(c);
      hvf[tl]  = hv;
      bf16 hb = (bf16)hv;
      hu[tl] = __builtin_bit_cast(unsigned short, hb);

      float t127 = hv * 127.f;
      float fhi  = rintf(t127);
      float flo  = fminf(fmaxf(rintf((t127 - fhi) * 256.f), -127.f), 127.f);
      int waddr = ((pw * 2 + 0) * 4 + cw) * 1024 + fl16 + tl * 4 + q;
      hsm[waddr]        = (char)(int)fhi;
      hsm[waddr + 4096] = (char)(int)flo;
    }

    // bf16 h for k_fc (plain cached stores, local-j layout)
    {
      const size_t obase = ((size_t)(bx * SEG + j) * 16 + m) * 128 + (size_t)(wv * 8);
#pragma unroll
      for (int tl = 0; tl < 4; ++tl) {
        int ov = __shfl_xor((int)(unsigned)hu[tl], 16);
        if ((q & 1) == 0) {
          unsigned dw = (unsigned)hu[tl] | ((unsigned)ov << 16);
          hseg_dw[obase + tl * 2 + (q >> 1)] = dw;
        }
      }
    }

    // prefetch next step's preacts
    if (j + 1 < SEG) {
      const f16* ip = xps + ((size_t)(dir * SEG + j + 1) * B_ + btile * 16 + m) * G4H + wv * 64 + q * 4;
#pragma unroll
      for (int tl = 0; tl < 4; ++tl) nxt[tl] = *(const half4*)(ip + tl * 16);
    }
  }

  // save carry state for next segment
  {
    floatx4* sp = (floatx4*)(state + ((size_t)bx * 1024 + tid) * 8);
    floatx4 s0, s1;
#pragma unroll
    for (int tl = 0; tl < 4; ++tl) { s0[tl] = cst[tl]; s1[tl] = hvf[tl]; }
    sp[0] = s0; sp[1] = s1;
  }
}

// ---------------- FC (per segment): accumulate dir partials into zeroed out ----------------
// Block j: dirc0 -> t = g0+j (adds fc_b), dirc1 -> t = T-1-g0-j. Ranges disjoint per launch;
// the other dir's contribution for the same t comes from a different (serialized) launch.
__global__ __launch_bounds__(512) void k_fc(const bf16* __restrict__ hseg,
                                            const float* __restrict__ fcw,
                                            const float* __restrict__ fcb,
                                            float* __restrict__ out, int seg)
{
  __shared__ float wsm[5 * 512];
  __shared__ unsigned short hl[64 * 258];
  const int tid = threadIdx.x;
  const int j   = blockIdx.x;
  for (int i = tid; i < 2560; i += 512) wsm[i] = fcw[i];
  const int o = tid / 64, b = tid & 63;
  for (int dirc = 0; dirc < 2; ++dirc) {
    __syncthreads();
    for (int i = tid; i < 8192; i += 512) {
      int bb = i >> 7, dd = i & 127;
      int gg = dirc * 4 + (bb >> 4), mmx = bb & 15;
      ((unsigned*)hl)[bb * 129 + dd] =
          ((const unsigned*)hseg)[((size_t)(gg * SEG + j) * 16 + mmx) * 128 + dd];
    }
    __syncthreads();
    if (tid < 320) {
      const float* wr = &wsm[o * 512 + dirc * 256];
      const unsigned short* hr = &hl[b * 258];
      float a = 0.f;
#pragma unroll 8
      for (int h = 0; h < 256; ++h) {
        unsigned u = ((unsigned)hr[h]) << 16;
        a += wr[h] * __builtin_bit_cast(float, u);
      }
      int tg = dirc ? (T_ - 1 - (seg * SEG + j)) : (seg * SEG + j);
      size_t oi = ((size_t)b * T_ + tg) * 5 + o;
      out[oi] += a + (dirc ? 0.f : fcb[o]);
    }
  }
}

// ---------------- launcher ----------------
extern "C" void kernel_launch(void* const* d_in, const int* in_sizes, int n_in,
                              void* d_out, int out_size, void* d_ws, size_t ws_size,
                              hipStream_t stream) {
  const float* x    = (const float*)d_in[0];
  const float* wihf = (const float*)d_in[1];
  const float* whhf = (const float*)d_in[2];
  const float* bihf = (const float*)d_in[3];
  const float* bhhf = (const float*)d_in[4];
  const float* wihb = (const float*)d_in[5];
  const float* whhb = (const float*)d_in[6];
  const float* bihb = (const float*)d_in[7];
  const float* bhhb = (const float*)d_in[8];
  const float* fcw  = (const float*)d_in[9];
  const float* fcb  = (const float*)d_in[10];
  float* out = (float*)d_out;

  char* ws = (char*)d_ws;
  bf16*  wihp  = (bf16*)(ws + 0);            //    655,360 B
  float* bsum  = (float*)(ws + 655360);      //      8,192 B
  int4v* whh8  = (int4v*)(ws + 663552);      //    524,288 B
  float* scl   = (float*)(ws + 1187840);     //        512 B
  f16*   xps   = (f16*)(ws + 1188352);       // 67,108,864 B  [dir][j][b][1024] per segment
  bf16*  hseg  = (bf16*)(ws + 68297216);     // 16,777,216 B  [g][j][m][hid] per segment
  float* state = (float*)(ws + 85074432);    //    262,144 B  (c,h) carry between segments
  (void)in_sizes; (void)n_in; (void)ws_size; // total 85,336,576 B < proven 89.8 MB

  hipMemsetAsync(out, 0, (size_t)out_size * sizeof(float), stream);
  k_pack_wih <<<640, 256, 0, stream>>>(wihf, wihb, wihp);
  k_pack_bias<<<8,   256, 0, stream>>>(bihf, bhhf, bihb, bhhb, bsum);
  k_pack_whh8<<<128, 256, 0, stream>>>(whhf, whhb, (char*)whh8, scl);
  for (int s = 0; s < NSEG; ++s) {
    k_xproj<<<512, 256, 0, stream>>>(x, wihp, bsum, xps, s);
    k_lstm <<<8,  1024, 0, stream>>>(whh8, scl, xps, hseg, state, s);
    k_fc   <<<256, 512, 0, stream>>>(hseg, fcw, fcb, out, s);
  }
}